// Round 4
// baseline (171.872 us; speedup 1.0000x reference)
//
#include <hip/hip_runtime.h>
#include <hip/hip_bf16.h>

// Pinball loss: mean over all elements of max((q-1)*(t-p), q*(t-p)), q = quantiles[0].
// preds, target: [128,512,288] f32 (18,874,368 elems each). Output: 1 f32 scalar.
// Memory-bound streaming reduction (reads 151 MB, writes 4 B).
//   R1: unroll x4 + single kernel + atomicAdd  -> null (56us kernel, 170us total).
//       => per-thread ILP not the limiter; harness restore/poison ~114us is fixed.
//   R4: per-block CONTIGUOUS segments (was grid-stride at 8MB strides) to give
//       each HBM channel long sequential bursts. Tests DRAM-row-locality theory.

#define BLOCK 256
#define GRID  2048

__device__ __forceinline__ float pin4(float4 t, float4 p, float q, float qm1) {
    float e0 = t.x - p.x;
    float e1 = t.y - p.y;
    float e2 = t.z - p.z;
    float e3 = t.w - p.w;
    return fmaxf(qm1 * e0, q * e0) + fmaxf(qm1 * e1, q * e1)
         + fmaxf(qm1 * e2, q * e2) + fmaxf(qm1 * e3, q * e3);
}

__global__ __launch_bounds__(BLOCK) void pinball_kernel(
    const float* __restrict__ preds,
    const float* __restrict__ target,
    const float* __restrict__ quantiles,
    float* __restrict__ out,       // [1], pre-zeroed by memset
    int n,                         // total element count
    float inv_n)
{
    const float q   = quantiles[0];
    const float qm1 = q - 1.0f;

    const int n4  = n >> 2;                                   // float4 count
    const int tid = threadIdx.x;

    // contiguous per-block segment [base, end) of float4 indices
    const int per_block = (n4 + (int)gridDim.x - 1) / (int)gridDim.x;  // 2304
    const int base = blockIdx.x * per_block;
    const int end  = min(base + per_block, n4);

    const float4* __restrict__ p4 = (const float4*)preds;
    const float4* __restrict__ t4 = (const float4*)target;

    float acc0 = 0.0f, acc1 = 0.0f, acc2 = 0.0f, acc3 = 0.0f;

    int i = base + tid;
    // main loop: 8 independent loads in flight, addresses sequential within block
    for (; i + 3 * BLOCK < end; i += 4 * BLOCK) {
        float4 pa = p4[i];
        float4 pb = p4[i +     BLOCK];
        float4 pc = p4[i + 2 * BLOCK];
        float4 pd = p4[i + 3 * BLOCK];
        float4 ta = t4[i];
        float4 tb = t4[i +     BLOCK];
        float4 tc = t4[i + 2 * BLOCK];
        float4 td = t4[i + 3 * BLOCK];
        acc0 += pin4(ta, pa, q, qm1);
        acc1 += pin4(tb, pb, q, qm1);
        acc2 += pin4(tc, pc, q, qm1);
        acc3 += pin4(td, pd, q, qm1);
    }
    // float4 tail within segment
    for (; i < end; i += BLOCK) {
        acc0 += pin4(t4[i], p4[i], q, qm1);
    }
    // scalar tail (n % 4 != 0 — not hit for this shape, but safe)
    if (blockIdx.x == 0) {
        for (int j = (n4 << 2) + tid; j < n; j += BLOCK) {
            float e = target[j] - preds[j];
            acc0 += fmaxf(qm1 * e, q * e);
        }
    }

    float acc = (acc0 + acc1) + (acc2 + acc3);

    // wave64 butterfly reduce
    #pragma unroll
    for (int off = 32; off > 0; off >>= 1)
        acc += __shfl_down(acc, off, 64);

    __shared__ float s[BLOCK / 64];
    const int lane = tid & 63;
    const int wid  = tid >> 6;
    if (lane == 0) s[wid] = acc;
    __syncthreads();
    if (tid == 0) {
        float b = (s[0] + s[1]) + (s[2] + s[3]);
        atomicAdd(out, b * inv_n);   // device-scope; 2048 adds total
    }
}

extern "C" void kernel_launch(void* const* d_in, const int* in_sizes, int n_in,
                              void* d_out, int out_size, void* d_ws, size_t ws_size,
                              hipStream_t stream) {
    const float* preds     = (const float*)d_in[0];
    const float* target    = (const float*)d_in[1];
    const float* quantiles = (const float*)d_in[2];
    float*       out       = (float*)d_out;

    const int n = in_sizes[0];
    const float inv_n = 1.0f / (float)n;

    hipMemsetAsync(out, 0, sizeof(float), stream);   // d_out is poisoned 0xAA
    pinball_kernel<<<GRID, BLOCK, 0, stream>>>(preds, target, quantiles, out, n, inv_n);
}

// Round 5
// 169.624 us; speedup vs baseline: 1.0132x; 1.0132x over previous
//
#include <hip/hip_runtime.h>
#include <hip/hip_bf16.h>

// Pinball loss: mean over all elements of max((q-1)*(t-p), q*(t-p)), q = quantiles[0].
// preds, target: [128,512,288] f32 (18,874,368 elems each). Output: 1 f32 scalar.
// Memory-bound streaming reduction (reads 151 MB, writes 4 B).
//   R1: unroll x4 + single kernel + atomicAdd       -> null (56us kernel).
//   R4: contiguous per-block segments               -> null (56-58us).
//       => not ILP, not locality. FETCH=73.75MB (half L3-hit), 2.7 TB/s effective.
//   R5: NON-TEMPORAL loads on both streams. Theory: harness's 144MiB restore-copy
//       leaves L2/L3 full of dirty lines; our streaming fills evict them ->
//       victim-writeback serializes with fetch. NT fills don't allocate/displace.

#define BLOCK 256
#define GRID  2048

typedef float v4f __attribute__((ext_vector_type(4)));

__device__ __forceinline__ float pin4(v4f t, v4f p, float q, float qm1) {
    float s = 0.0f;
    #pragma unroll
    for (int k = 0; k < 4; ++k) {
        float e = t[k] - p[k];
        s += fmaxf(qm1 * e, q * e);
    }
    return s;
}

__global__ __launch_bounds__(BLOCK) void pinball_kernel(
    const float* __restrict__ preds,
    const float* __restrict__ target,
    const float* __restrict__ quantiles,
    float* __restrict__ out,       // [1], pre-zeroed by memset
    int n,                         // total element count
    float inv_n)
{
    const float q   = quantiles[0];
    const float qm1 = q - 1.0f;

    const int n4  = n >> 2;                                   // float4 count
    const int tid = threadIdx.x;

    // contiguous per-block segment [base, end) of float4 indices
    const int per_block = (n4 + (int)gridDim.x - 1) / (int)gridDim.x;  // 2304
    const int base = blockIdx.x * per_block;
    const int end  = min(base + per_block, n4);

    const v4f* __restrict__ p4 = (const v4f*)preds;
    const v4f* __restrict__ t4 = (const v4f*)target;

    float acc0 = 0.0f, acc1 = 0.0f, acc2 = 0.0f, acc3 = 0.0f;

    int i = base + tid;
    // main loop: 8 independent NT loads in flight, sequential within block
    for (; i + 3 * BLOCK < end; i += 4 * BLOCK) {
        v4f pa = __builtin_nontemporal_load(p4 + i);
        v4f pb = __builtin_nontemporal_load(p4 + i +     BLOCK);
        v4f pc = __builtin_nontemporal_load(p4 + i + 2 * BLOCK);
        v4f pd = __builtin_nontemporal_load(p4 + i + 3 * BLOCK);
        v4f ta = __builtin_nontemporal_load(t4 + i);
        v4f tb = __builtin_nontemporal_load(t4 + i +     BLOCK);
        v4f tc = __builtin_nontemporal_load(t4 + i + 2 * BLOCK);
        v4f td = __builtin_nontemporal_load(t4 + i + 3 * BLOCK);
        acc0 += pin4(ta, pa, q, qm1);
        acc1 += pin4(tb, pb, q, qm1);
        acc2 += pin4(tc, pc, q, qm1);
        acc3 += pin4(td, pd, q, qm1);
    }
    // float4 tail within segment
    for (; i < end; i += BLOCK) {
        v4f p = __builtin_nontemporal_load(p4 + i);
        v4f t = __builtin_nontemporal_load(t4 + i);
        acc0 += pin4(t, p, q, qm1);
    }
    // scalar tail (n % 4 != 0 — not hit for this shape, but safe)
    if (blockIdx.x == 0) {
        for (int j = (n4 << 2) + tid; j < n; j += BLOCK) {
            float e = target[j] - preds[j];
            acc0 += fmaxf(qm1 * e, q * e);
        }
    }

    float acc = (acc0 + acc1) + (acc2 + acc3);

    // wave64 butterfly reduce
    #pragma unroll
    for (int off = 32; off > 0; off >>= 1)
        acc += __shfl_down(acc, off, 64);

    __shared__ float s[BLOCK / 64];
    const int lane = tid & 63;
    const int wid  = tid >> 6;
    if (lane == 0) s[wid] = acc;
    __syncthreads();
    if (tid == 0) {
        float b = (s[0] + s[1]) + (s[2] + s[3]);
        atomicAdd(out, b * inv_n);   // device-scope; 2048 adds total
    }
}

extern "C" void kernel_launch(void* const* d_in, const int* in_sizes, int n_in,
                              void* d_out, int out_size, void* d_ws, size_t ws_size,
                              hipStream_t stream) {
    const float* preds     = (const float*)d_in[0];
    const float* target    = (const float*)d_in[1];
    const float* quantiles = (const float*)d_in[2];
    float*       out       = (float*)d_out;

    const int n = in_sizes[0];
    const float inv_n = 1.0f / (float)n;

    hipMemsetAsync(out, 0, sizeof(float), stream);   // d_out is poisoned 0xAA
    pinball_kernel<<<GRID, BLOCK, 0, stream>>>(preds, target, quantiles, out, n, inv_n);
}